// Round 12
// baseline (311.381 us; speedup 1.0000x reference)
//
#include <hip/hip_runtime.h>
#include <hip/hip_bf16.h>

#define B_NUM 2
#define S_LEN 2048
#define E_DIM 1024
#define H_NUM 16
#define D_DIM 64
#define QKV_LD 3072
// 1/sqrt(64) * log2(e): folded so softmax exp is a bare v_exp_f32 (exp2)
#define QSCALE_LOG2E 0.18033688011112042f

typedef __attribute__((ext_vector_type(8))) short bf16x8;
typedef __attribute__((ext_vector_type(8))) unsigned short u16x8;
typedef __attribute__((ext_vector_type(4))) unsigned short u16x4;
typedef __attribute__((ext_vector_type(4))) float f32x4;
typedef __attribute__((ext_vector_type(16))) float f32x16;
typedef __attribute__((ext_vector_type(2))) int i32x2;

static __device__ __forceinline__ unsigned short f2bf(float f) {
    union { float f; unsigned int u; } v; v.f = f;
    unsigned int r = v.u + 0x7fffu + ((v.u >> 16) & 1u);   // RNE
    return (unsigned short)(r >> 16);
}

static __device__ __forceinline__ unsigned cvtpk_bf16(float lo, float hi) {
    unsigned r;
    asm("v_cvt_pk_bf16_f32 %0, %1, %2" : "=v"(r) : "v"(lo), "v"(hi));
    return r;
}

static __device__ __forceinline__ void keep_alive8(bf16x8 v) {
    union { bf16x8 v; unsigned u[4]; } k; k.v = v;
    asm volatile("" :: "v"(k.u[0]), "v"(k.u[1]), "v"(k.u[2]), "v"(k.u[3]));
}

// async global->LDS, 16B per lane; LDS dest = uniform base + lane*16
static __device__ __forceinline__ void gload16(const void* gsrc, void* ldst) {
    __builtin_amdgcn_global_load_lds(
        (const __attribute__((address_space(1))) unsigned int*)gsrc,
        (__attribute__((address_space(3))) unsigned int*)ldst, 16, 0, 0);
}

// ---------------------------------------------------------------------------
// fp32 -> bf16 bulk convert
// ---------------------------------------------------------------------------
__global__ __launch_bounds__(256)
void cvt_f32_bf16(const float* __restrict__ in, unsigned short* __restrict__ outp, int n4) {
    int i = blockIdx.x * blockDim.x + threadIdx.x;
    if (i < n4) {
        float4 f = ((const float4*)in)[i];
        u16x4 o = { f2bf(f.x), f2bf(f.y), f2bf(f.z), f2bf(f.w) };
        ((u16x4*)outp)[i] = o;
    }
}

// ---------------------------------------------------------------------------
// 128x128 bf16 MFMA GEMM, BK=64, 4 waves. (proven rounds 4-11)
// ---------------------------------------------------------------------------
template <bool OUT_BF16, bool QSCALE>
__global__ __launch_bounds__(256)
void gemm_bt_mfma128(const unsigned short* __restrict__ A,
                     const unsigned short* __restrict__ Bw,
                     void* __restrict__ Cv, int M, int N, int K) {
    __shared__ unsigned short As[128 * 64];
    __shared__ unsigned short Bs[128 * 64];
    char* const AsB = (char*)As;
    char* const BsB = (char*)Bs;
    const int tid  = threadIdx.x;
    const int lane = tid & 63;
    const int w    = tid >> 6;
    const int lg   = lane >> 4;
    const int lq   = lane & 15;
    const int bm = blockIdx.y * 128;
    const int bn = blockIdx.x * 128;
    const int wr = (w >> 1) * 64;
    const int wc = (w & 1) * 64;
    const int lrow8 = lane >> 3;
    const int gblk  = (lane & 7) ^ lrow8;

    f32x4 acc[4][4];
#pragma unroll
    for (int i = 0; i < 4; ++i)
#pragma unroll
        for (int j = 0; j < 4; ++j) acc[i][j] = (f32x4){0.f, 0.f, 0.f, 0.f};

    for (int k0 = 0; k0 < K; k0 += 64) {
        __syncthreads();
#pragma unroll
        for (int t = 0; t < 4; ++t) {
            const int c = w * 4 + t;
            const int row = c * 8 + lrow8;
            gload16(A + (size_t)(bm + row) * K + k0 + gblk * 8, AsB + c * 1024);
            gload16(Bw + (size_t)(bn + row) * K + k0 + gblk * 8, BsB + c * 1024);
        }
        __syncthreads();

        bf16x8 af[4][2], bfr[4][2];
#pragma unroll
        for (int rt = 0; rt < 4; ++rt) {
            const int row = wr + rt * 16 + lq;
            const int sz = (row & 7) << 4;
            af[rt][0] = *(const bf16x8*)(AsB + row * 128 + ((lg * 16)      ^ sz));
            af[rt][1] = *(const bf16x8*)(AsB + row * 128 + ((64 + lg * 16) ^ sz));
        }
#pragma unroll
        for (int ct = 0; ct < 4; ++ct) {
            const int row = wc + ct * 16 + lq;
            const int sz = (row & 7) << 4;
            bfr[ct][0] = *(const bf16x8*)(BsB + row * 128 + ((lg * 16)      ^ sz));
            bfr[ct][1] = *(const bf16x8*)(BsB + row * 128 + ((64 + lg * 16) ^ sz));
        }
#pragma unroll
        for (int rt = 0; rt < 4; ++rt)
#pragma unroll
            for (int ct = 0; ct < 4; ++ct) {
                acc[rt][ct] = __builtin_amdgcn_mfma_f32_16x16x32_bf16(af[rt][0], bfr[ct][0], acc[rt][ct], 0, 0, 0);
                acc[rt][ct] = __builtin_amdgcn_mfma_f32_16x16x32_bf16(af[rt][1], bfr[ct][1], acc[rt][ct], 0, 0, 0);
            }
    }

#pragma unroll
    for (int rt = 0; rt < 4; ++rt)
#pragma unroll
        for (int ct = 0; ct < 4; ++ct) {
            const int row = bm + wr + rt * 16 + lg * 4;
            const int col = bn + wc + ct * 16 + lq;
            float scale = 1.f;
            if constexpr (QSCALE) scale = ((col % 192) < 64) ? QSCALE_LOG2E : 1.f;
#pragma unroll
            for (int r = 0; r < 4; ++r) {
                float vv = acc[rt][ct][r] * scale;
                if constexpr (OUT_BF16)
                    ((unsigned short*)Cv)[(size_t)(row + r) * N + col] = f2bf(vv);
                else
                    ((float*)Cv)[(size_t)(row + r) * N + col] = vv;
            }
        }
}

// ---------------------------------------------------------------------------
// 64x64 bf16 MFMA GEMM (known-good; output projection)
// ---------------------------------------------------------------------------
template <bool OUT_BF16, bool QSCALE>
__global__ __launch_bounds__(256)
void gemm_bt_mfma(const unsigned short* __restrict__ A,
                  const unsigned short* __restrict__ Bw,
                  void* __restrict__ Cv, int M, int N, int K) {
    __shared__ unsigned short As[64 * 64];
    __shared__ unsigned short Bs[64 * 64];
    char* const AsB = (char*)As;
    char* const BsB = (char*)Bs;
    const int tid  = threadIdx.x;
    const int lane = tid & 63;
    const int w    = tid >> 6;
    const int lg   = lane >> 4;
    const int lq   = lane & 15;
    const int bm = blockIdx.y * 64;
    const int bn = blockIdx.x * 64;
    const int wr = (w >> 1) * 32;
    const int wc = (w & 1) * 32;
    const int sr = tid >> 2;
    const int sc = (tid & 3) * 16;
    const int swzS = (sr & 7) << 4;

    f32x4 acc[2][2];
#pragma unroll
    for (int i = 0; i < 2; ++i)
#pragma unroll
        for (int j = 0; j < 2; ++j) acc[i][j] = (f32x4){0.f, 0.f, 0.f, 0.f};

    const unsigned short* ap = A  + (size_t)(bm + sr) * K + sc;
    const unsigned short* bp = Bw + (size_t)(bn + sr) * K + sc;

    for (int k0 = 0; k0 < K; k0 += 64) {
        __syncthreads();
        u16x8 av0 = *(const u16x8*)(ap + k0);
        u16x8 av1 = *(const u16x8*)(ap + k0 + 8);
        u16x8 bv0 = *(const u16x8*)(bp + k0);
        u16x8 bv1 = *(const u16x8*)(bp + k0 + 8);
        *(u16x8*)(AsB + sr * 128 + ((sc * 2)      ^ swzS)) = av0;
        *(u16x8*)(AsB + sr * 128 + ((sc * 2 + 16) ^ swzS)) = av1;
        *(u16x8*)(BsB + sr * 128 + ((sc * 2)      ^ swzS)) = bv0;
        *(u16x8*)(BsB + sr * 128 + ((sc * 2 + 16) ^ swzS)) = bv1;
        __syncthreads();

        bf16x8 af[2][2], bfr[2][2];
#pragma unroll
        for (int rt = 0; rt < 2; ++rt) {
            const int row = wr + rt * 16 + lq;
            const int sz = (row & 7) << 4;
            af[rt][0] = *(const bf16x8*)(AsB + row * 128 + ((lg * 16)      ^ sz));
            af[rt][1] = *(const bf16x8*)(AsB + row * 128 + ((64 + lg * 16) ^ sz));
        }
#pragma unroll
        for (int ct = 0; ct < 2; ++ct) {
            const int row = wc + ct * 16 + lq;
            const int sz = (row & 7) << 4;
            bfr[ct][0] = *(const bf16x8*)(BsB + row * 128 + ((lg * 16)      ^ sz));
            bfr[ct][1] = *(const bf16x8*)(BsB + row * 128 + ((64 + lg * 16) ^ sz));
        }
#pragma unroll
        for (int rt = 0; rt < 2; ++rt)
#pragma unroll
            for (int ct = 0; ct < 2; ++ct) {
                acc[rt][ct] = __builtin_amdgcn_mfma_f32_16x16x32_bf16(af[rt][0], bfr[ct][0], acc[rt][ct], 0, 0, 0);
                acc[rt][ct] = __builtin_amdgcn_mfma_f32_16x16x32_bf16(af[rt][1], bfr[ct][1], acc[rt][ct], 0, 0, 0);
            }
    }

#pragma unroll
    for (int rt = 0; rt < 2; ++rt)
#pragma unroll
        for (int ct = 0; ct < 2; ++ct) {
            const int row = bm + wr + rt * 16 + lg * 4;
            const int col = bn + wc + ct * 16 + lq;
            float scale = 1.f;
            if constexpr (QSCALE) scale = ((col % 192) < 64) ? QSCALE_LOG2E : 1.f;
#pragma unroll
            for (int r = 0; r < 4; ++r) {
                float vv = acc[rt][ct][r] * scale;
                if constexpr (OUT_BF16)
                    ((unsigned short*)Cv)[(size_t)(row + r) * N + col] = f2bf(vv);
                else
                    ((float*)Cv)[(size_t)(row + r) * N + col] = vv;
            }
        }
}

// ---------------------------------------------------------------------------
// Flash attention v7 (REAL, best known: 72.0 us). Counted-vmcnt pipeline,
// no-max softmax, 2-buf V + 3-buf K. Unchanged from round 7.
// ---------------------------------------------------------------------------
__global__ __launch_bounds__(256)
void attn_v7(const unsigned short* __restrict__ qkv, const int* __restrict__ mask,
             unsigned short* __restrict__ vout) {
    __shared__ __align__(16) char KsP[3][8192];
    __shared__ __align__(16) char VtP[2][8192];
    __shared__ __align__(16) float BiasF[S_LEN];

    const int tid  = threadIdx.x;
    const int lane = tid & 63;
    const int w    = tid >> 6;
    const int ln   = lane & 31;
    const int hi   = lane >> 5;
    const int q0 = blockIdx.x * 128;
    const int h  = blockIdx.y;
    const int b  = blockIdx.z;
    const unsigned short* const kv =
        qkv + (size_t)b * S_LEN * QKV_LD + (size_t)h * (3 * D_DIM);

    {
        const int4* mr = (const int4*)(mask + (size_t)b * S_LEN);
        int4 m0 = mr[tid * 2];
        int4 m1 = mr[tid * 2 + 1];
        float4 f0 = { m0.x ? 0.f : -30000.f, m0.y ? 0.f : -30000.f,
                      m0.z ? 0.f : -30000.f, m0.w ? 0.f : -30000.f };
        float4 f1 = { m1.x ? 0.f : -30000.f, m1.y ? 0.f : -30000.f,
                      m1.z ? 0.f : -30000.f, m1.w ? 0.f : -30000.f };
        ((float4*)BiasF)[tid * 2]     = f0;
        ((float4*)BiasF)[tid * 2 + 1] = f1;
    }

    bf16x8 qf[4];
    {
        const unsigned short* qp = kv + (size_t)(q0 + w * 32 + ln) * QKV_LD + hi * 8;
#pragma unroll
        for (int kk = 0; kk < 4; ++kk)
            qf[kk] = *(const bf16x8*)(qp + kk * 16);
    }

    const int lrow8 = lane >> 3;
    const int gblk  = (lane & 7) ^ lrow8;
    const int vkb = (tid & 15) * 4;
    const int vdb = (tid >> 4) * 4;

    {
#pragma unroll
        for (int t = 0; t < 2; ++t) {
            const int c = w * 2 + t;
            gload16(kv + (size_t)(c * 8 + lrow8) * QKV_LD + D_DIM + gblk * 8,
                    KsP[0] + c * 1024);
            gload16(kv + (size_t)(64 + c * 8 + lrow8) * QKV_LD + D_DIM + gblk * 8,
                    KsP[1] + c * 1024);
        }
        u16x4 vr[4];
#pragma unroll
        for (int i = 0; i < 4; ++i)
            vr[i] = *(const u16x4*)(kv + (size_t)(vkb + i) * QKV_LD + 2 * D_DIM + vdb);
#pragma unroll
        for (int j = 0; j < 4; ++j) {
            u16x4 o = { vr[0][j], vr[1][j], vr[2][j], vr[3][j] };
            const int row = vdb + j;
            *(u16x4*)(VtP[0] + row * 128 + ((vkb * 2) ^ ((row & 7) << 4))) = o;
        }
    }
    __builtin_amdgcn_sched_barrier(0);
    asm volatile("s_waitcnt vmcnt(0) lgkmcnt(0)" ::: "memory");
    __builtin_amdgcn_s_barrier();
    __builtin_amdgcn_sched_barrier(0);

    f32x16 accO[2];
#pragma unroll
    for (int dt = 0; dt < 2; ++dt)
#pragma unroll
        for (int r = 0; r < 16; ++r) accO[dt][r] = 0.f;
    f32x4 rsumv = (f32x4){0.f, 0.f, 0.f, 0.f};

    const int NT = S_LEN / 64;
    int cur3 = 0;
    int k2b  = 2;
    for (int it = 0; it < NT; ++it) {
        const int curv = it & 1;
        const int kv0 = it * 64;
        char* const KsC = KsP[cur3];
        char* const VtC = VtP[curv];
        const bool pfV = (it + 1 < NT);
        const bool pfK = (it + 2 < NT);

        u16x4 vr[4];
        if (pfV) {
            const int kvn = kv0 + 64;
#pragma unroll
            for (int i = 0; i < 4; ++i)
                vr[i] = *(const u16x4*)(kv + (size_t)(kvn + vkb + i) * QKV_LD + 2 * D_DIM + vdb);
        }
        if (pfK) {
            const int kvn2 = kv0 + 128;
#pragma unroll
            for (int t = 0; t < 2; ++t) {
                const int c = w * 2 + t;
                gload16(kv + (size_t)(kvn2 + c * 8 + lrow8) * QKV_LD + D_DIM + gblk * 8,
                        KsP[k2b] + c * 1024);
            }
        }

        f32x16 s[2];
#pragma unroll
        for (int ks = 0; ks < 2; ++ks)
#pragma unroll
            for (int m = 0; m < 4; ++m) {
                f32x4 b4 = *(const f32x4*)(&BiasF[kv0 + ks * 32 + m * 8 + hi * 4]);
#pragma unroll
                for (int i = 0; i < 4; ++i) s[ks][m * 4 + i] = b4[i];
            }
        __builtin_amdgcn_s_setprio(1);
#pragma unroll
        for (int ks = 0; ks < 2; ++ks) {
            const int krow = ks * 32 + ln;
            const int swz = (ln & 7) << 4;
#pragma unroll
            for (int kk = 0; kk < 4; ++kk) {
                bf16x8 kf = *(const bf16x8*)(KsC + krow * 128 + (((kk * 16 + hi * 8) * 2) ^ swz));
                s[ks] = __builtin_amdgcn_mfma_f32_32x32x16_bf16(kf, qf[kk], s[ks], 0, 0, 0);
            }
        }
        __builtin_amdgcn_s_setprio(0);

#pragma unroll
        for (int ks = 0; ks < 2; ++ks)
#pragma unroll
            for (int r = 0; r < 16; ++r) {
                float p = __builtin_amdgcn_exp2f(s[ks][r]);
                s[ks][r] = p;
                rsumv[r & 3] += p;
            }

        bf16x8 pb[4];
#pragma unroll
        for (int ks = 0; ks < 2; ++ks) {
            unsigned wA[4], wB[4];
#pragma unroll
            for (int m = 0; m < 4; ++m) {
                wA[m] = cvtpk_bf16(s[ks][4 * m + 0], s[ks][4 * m + 1]);
                wB[m] = cvtpk_bf16(s[ks][4 * m + 2], s[ks][4 * m + 3]);
            }
#pragma unroll
            for (int t = 0; t < 2; ++t) {
                i32x2 ra = __builtin_amdgcn_permlane32_swap((int)wA[2 * t], (int)wA[2 * t + 1], false, false);
                i32x2 rb = __builtin_amdgcn_permlane32_swap((int)wB[2 * t], (int)wB[2 * t + 1], false, false);
                union { unsigned u[4]; bf16x8 v; } uu;
                uu.u[0] = (unsigned)ra[0];
                uu.u[1] = (unsigned)rb[0];
                uu.u[2] = (unsigned)ra[1];
                uu.u[3] = (unsigned)rb[1];
                pb[ks * 2 + t] = uu.v;
            }
        }

        __builtin_amdgcn_s_setprio(1);
#pragma unroll
        for (int dt = 0; dt < 2; ++dt) {
            const int drow = dt * 32 + ln;
            const int swz = (ln & 7) << 4;
#pragma unroll
            for (int n = 0; n < 4; ++n) {
                bf16x8 va = *(const bf16x8*)(VtC + drow * 128 + (((n * 16 + hi * 8) * 2) ^ swz));
                accO[dt] = __builtin_amdgcn_mfma_f32_32x32x16_bf16(va, pb[n], accO[dt], 0, 0, 0);
            }
        }
        __builtin_amdgcn_s_setprio(0);

        if (pfV) {
#pragma unroll
            for (int j = 0; j < 4; ++j) {
                u16x4 o = { vr[0][j], vr[1][j], vr[2][j], vr[3][j] };
                const int row = vdb + j;
                *(u16x4*)(VtP[curv ^ 1] + row * 128 + ((vkb * 2) ^ ((row & 7) << 4))) = o;
            }
            __builtin_amdgcn_sched_barrier(0);
            asm volatile("s_waitcnt lgkmcnt(0)" ::: "memory");
            __builtin_amdgcn_s_barrier();
            __builtin_amdgcn_sched_barrier(0);
        }

        cur3 = (cur3 == 2) ? 0 : cur3 + 1;
        k2b  = (k2b  == 2) ? 0 : k2b  + 1;
    }

    float rsum = rsumv[0] + rsumv[1] + rsumv[2] + rsumv[3];
    {
        i32x2 rr = __builtin_amdgcn_permlane32_swap(__float_as_int(rsum), __float_as_int(rsum), false, false);
        rsum = __int_as_float(rr[0]) + __int_as_float(rr[1]);
    }
    const float inv = 1.f / rsum;
    unsigned short* op = vout + (size_t)(b * S_LEN + q0 + w * 32 + ln) * E_DIM + h * D_DIM;
#pragma unroll
    for (int dt = 0; dt < 2; ++dt)
#pragma unroll
        for (int m = 0; m < 4; ++m) {
            u16x4 o;
#pragma unroll
            for (int i = 0; i < 4; ++i) o[i] = f2bf(accO[dt][4 * m + i] * inv);
            *(u16x4*)(op + dt * 32 + m * 8 + hi * 4) = o;
        }
}

// ---------------------------------------------------------------------------
// ABLATION PROBES: v6 body (2-buf, 1 barrier/tile — round-6 kernel, 73.5 us)
// with phases removed per VAR. Output goes to scratch; asm keep-alives
// prevent DCE of upstream phases (rule #17).
//   VAR 0: full body (within-build baseline)
//   VAR 1: no exp2 (p = s)          -> marginal cost of TRANS+dependency
//   VAR 2: no V staging, no PV      -> marginal cost of the whole PV path
//   VAR 3: no K staging, no QK      -> marginal cost of the whole QK path
// ---------------------------------------------------------------------------
template <int VAR>
__global__ __launch_bounds__(256)
void attn_probe(const unsigned short* __restrict__ qkv, const int* __restrict__ mask,
                unsigned short* __restrict__ vout) {
    __shared__ __align__(16) char KsP[2][8192];
    __shared__ __align__(16) char VtP[2][8192];
    __shared__ __align__(16) float BiasF[S_LEN];

    const int tid  = threadIdx.x;
    const int lane = tid & 63;
    const int w    = tid >> 6;
    const int ln   = lane & 31;
    const int hi   = lane >> 5;
    const int q0 = blockIdx.x * 128;
    const int h  = blockIdx.y;
    const int b  = blockIdx.z;
    const unsigned short* const kv =
        qkv + (size_t)b * S_LEN * QKV_LD + (size_t)h * (3 * D_DIM);

    {
        const int4* mr = (const int4*)(mask + (size_t)b * S_LEN);
        int4 m0 = mr[tid * 2];
        int4 m1 = mr[tid * 2 + 1];
        float4 f0 = { m0.x ? 0.f : -30000.f, m0.y ? 0.f : -30000.f,
                      m0.z ? 0.f : -30000.f, m0.w ? 0.f : -30000.f };
        float4 f1 = { m1.x ? 0.f : -30000.f, m1.y ? 0.f : -30000.f,
                      m1.z ? 0.f : -30000.f, m1.w ? 0.f : -30000.f };
        ((float4*)BiasF)[tid * 2]     = f0;
        ((float4*)BiasF)[tid * 2 + 1] = f1;
    }

    bf16x8 qf[4];
    {
        const unsigned short* qp = kv + (size_t)(q0 + w * 32 + ln) * QKV_LD + hi * 8;
#pragma unroll
        for (int kk = 0; kk < 4; ++kk)
            qf[kk] = *(const bf16x8*)(qp + kk * 16);
    }

    const int lrow8 = lane >> 3;
    const int gblk  = (lane & 7) ^ lrow8;
    const int vkb = (tid & 15) * 4;
    const int vdb = (tid >> 4) * 4;

    {   // stage tile 0
        if constexpr (VAR != 3) {
#pragma unroll
            for (int t = 0; t < 2; ++t) {
                const int c = w * 2 + t;
                gload16(kv + (size_t)(c * 8 + lrow8) * QKV_LD + D_DIM + gblk * 8,
                        KsP[0] + c * 1024);
            }
        }
        if constexpr (VAR != 2) {
            u16x4 vr[4];
#pragma unroll
            for (int i = 0; i < 4; ++i)
                vr[i] = *(const u16x4*)(kv + (size_t)(vkb + i) * QKV_LD + 2 * D_DIM + vdb);
#pragma unroll
            for (int j = 0; j < 4; ++j) {
                u16x4 o = { vr[0][j], vr[1][j], vr[2][j], vr[3][j] };
                const int row = vdb + j;
                *(u16x4*)(VtP[0] + row * 128 + ((vkb * 2) ^ ((row & 7) << 4))) = o;
            }
        }
    }
    __syncthreads();

    f32x16 accO[2];
#pragma unroll
    for (int dt = 0; dt < 2; ++dt)
#pragma unroll
        for (int r = 0; r < 16; ++r) accO[dt][r] = 0.f;
    f32x4 rsumv = (f32x4){0.f, 0.f, 0.f, 0.f};

    for (int it = 0; it < S_LEN / 64; ++it) {
        const int cur = it & 1;
        const int kv0 = it * 64;
        char* const KsC = KsP[cur];
        char* const VtC = VtP[cur];
        const bool pf = (it < S_LEN / 64 - 1);

        u16x4 vr[4];
        if (pf) {
            const int kvn = kv0 + 64;
            if constexpr (VAR != 3) {
#pragma unroll
                for (int t = 0; t < 2; ++t) {
                    const int c = w * 2 + t;
                    gload16(kv + (size_t)(kvn + c * 8 + lrow8) * QKV_LD + D_DIM + gblk * 8,
                            KsP[cur ^ 1] + c * 1024);
                }
            }
            if constexpr (VAR != 2) {
#pragma unroll
                for (int i = 0; i < 4; ++i)
                    vr[i] = *(const u16x4*)(kv + (size_t)(kvn + vkb + i) * QKV_LD + 2 * D_DIM + vdb);
            }
        }

        f32x16 s[2];
#pragma unroll
        for (int ks = 0; ks < 2; ++ks)
#pragma unroll
            for (int m = 0; m < 4; ++m) {
                f32x4 b4 = *(const f32x4*)(&BiasF[kv0 + ks * 32 + m * 8 + hi * 4]);
#pragma unroll
                for (int i = 0; i < 4; ++i) s[ks][m * 4 + i] = b4[i];
            }
        if constexpr (VAR != 3) {
            __builtin_amdgcn_s_setprio(1);
#pragma unroll
            for (int ks = 0; ks < 2; ++ks) {
                const int krow = ks * 32 + ln;
                const int swz = (ln & 7) << 4;
#pragma unroll
                for (int kk = 0; kk < 4; ++kk) {
                    bf16x8 kf = *(const bf16x8*)(KsC + krow * 128 + (((kk * 16 + hi * 8) * 2) ^ swz));
                    s[ks] = __builtin_amdgcn_mfma_f32_32x32x16_bf16(kf, qf[kk], s[ks], 0, 0, 0);
                }
            }
            __builtin_amdgcn_s_setprio(0);
        }

#pragma unroll
        for (int ks = 0; ks < 2; ++ks)
#pragma unroll
            for (int r = 0; r < 16; ++r) {
                float p = (VAR == 1) ? s[ks][r] : __builtin_amdgcn_exp2f(s[ks][r]);
                s[ks][r] = p;
                rsumv[r & 3] += p;
            }

        bf16x8 pb[4];
#pragma unroll
        for (int ks = 0; ks < 2; ++ks) {
            unsigned wA[4], wB[4];
#pragma unroll
            for (int m = 0; m < 4; ++m) {
                wA[m] = cvtpk_bf16(s[ks][4 * m + 0], s[ks][4 * m + 1]);
                wB[m] = cvtpk_bf16(s[ks][4 * m + 2], s[ks][4 * m + 3]);
            }
#pragma unroll
            for (int t = 0; t < 2; ++t) {
                i32x2 ra = __builtin_amdgcn_permlane32_swap((int)wA[2 * t], (int)wA[2 * t + 1], false, false);
                i32x2 rb = __builtin_amdgcn_permlane32_swap((int)wB[2 * t], (int)wB[2 * t + 1], false, false);
                union { unsigned u[4]; bf16x8 v; } uu;
                uu.u[0] = (unsigned)ra[0];
                uu.u[1] = (unsigned)rb[0];
                uu.u[2] = (unsigned)ra[1];
                uu.u[3] = (unsigned)rb[1];
                pb[ks * 2 + t] = uu.v;
            }
        }

        if constexpr (VAR != 2) {
            __builtin_amdgcn_s_setprio(1);
#pragma unroll
            for (int dt = 0; dt < 2; ++dt) {
                const int drow = dt * 32 + ln;
                const int swz = (ln & 7) << 4;
#pragma unroll
                for (int n = 0; n < 4; ++n) {
                    bf16x8 va = *(const bf16x8*)(VtC + drow * 128 + (((n * 16 + hi * 8) * 2) ^ swz));
                    accO[dt] = __builtin_amdgcn_mfma_f32_32x32x16_bf16(va, pb[n], accO[dt], 0, 0, 0);
                }
            }
            __builtin_amdgcn_s_setprio(0);
        } else {
            keep_alive8(pb[0]); keep_alive8(pb[1]);
            keep_alive8(pb[2]); keep_alive8(pb[3]);
        }

        if (pf) {
            if constexpr (VAR != 2) {
#pragma unroll
                for (int j = 0; j < 4; ++j) {
                    u16x4 o = { vr[0][j], vr[1][j], vr[2][j], vr[3][j] };
                    const int row = vdb + j;
                    *(u16x4*)(VtP[cur ^ 1] + row * 128 + ((vkb * 2) ^ ((row & 7) << 4))) = o;
                }
            }
        }
        __syncthreads();
    }

    float rsum = rsumv[0] + rsumv[1] + rsumv[2] + rsumv[3];
    {
        i32x2 rr = __builtin_amdgcn_permlane32_swap(__float_as_int(rsum), __float_as_int(rsum), false, false);
        rsum = __int_as_float(rr[0]) + __int_as_float(rr[1]);
    }
    const float inv = 1.f / rsum;
    unsigned short* op = vout + (size_t)(b * S_LEN + q0 + w * 32 + ln) * E_DIM + h * D_DIM;
#pragma unroll
    for (int dt = 0; dt < 2; ++dt)
#pragma unroll
        for (int m = 0; m < 4; ++m) {
            u16x4 o;
#pragma unroll
            for (int i = 0; i < 4; ++i) o[i] = f2bf(accO[dt][4 * m + i] * inv);
            *(u16x4*)(op + dt * 32 + m * 8 + hi * 4) = o;
        }
}

// ---------------------------------------------------------------------------
extern "C" void kernel_launch(void* const* d_in, const int* in_sizes, int n_in,
                              void* d_out, int out_size, void* d_ws, size_t ws_size,
                              hipStream_t stream) {
    const float* x      = (const float*)d_in[0];
    const int*   mask   = (const int*)d_in[1];
    const float* w_qkv  = (const float*)d_in[2];
    const float* w_o    = (const float*)d_in[3];
    float*       out    = (float*)d_out;

    const int M = B_NUM * S_LEN;     // 4096
    unsigned short* qkvb = (unsigned short*)d_ws;                    // M x 3E
    unsigned short* vbuf = qkvb + (size_t)M * 3 * E_DIM;             // M x E
    unsigned short* xb   = vbuf + (size_t)M * E_DIM;                 // M x E (probe scratch after use)
    unsigned short* wqb  = xb   + (size_t)M * E_DIM;                 // 3E x E
    unsigned short* wob  = wqb  + (size_t)3 * E_DIM * E_DIM;         // E x E

    dim3 blk(256);
    {
        int n4;
        n4 = M * E_DIM / 4;
        cvt_f32_bf16<<<dim3((n4 + 255) / 256), blk, 0, stream>>>(x, xb, n4);
        n4 = 3 * E_DIM * E_DIM / 4;
        cvt_f32_bf16<<<dim3((n4 + 255) / 256), blk, 0, stream>>>(w_qkv, wqb, n4);
        n4 = E_DIM * E_DIM / 4;
        cvt_f32_bf16<<<dim3((n4 + 255) / 256), blk, 0, stream>>>(w_o, wob, n4);
    }

    // QKV projection (q columns pre-scaled by 0.125*log2e), bf16 out
    gemm_bt_mfma128<true, true><<<dim3(3 * E_DIM / 128, M / 128), blk, 0, stream>>>(
        xb, wqb, qkvb, M, 3 * E_DIM, E_DIM);

    // flash attention v7 (real)
    attn_v7<<<dim3(S_LEN / 128, H_NUM, B_NUM), blk, 0, stream>>>(qkvb, mask, vbuf);

    // output projection, fp32 out
    gemm_bt_mfma<false, false><<<dim3(E_DIM / 64, M / 64), blk, 0, stream>>>(
        vbuf, wob, out, M, E_DIM, E_DIM);

    // ---- ablation probes (write to xb scratch; xb is dead after gemm128) ----
    dim3 pgrid(S_LEN / 128, H_NUM, B_NUM);
    attn_probe<0><<<pgrid, blk, 0, stream>>>(qkvb, mask, xb);
    attn_probe<1><<<pgrid, blk, 0, stream>>>(qkvb, mask, xb);
    attn_probe<2><<<pgrid, blk, 0, stream>>>(qkvb, mask, xb);
    attn_probe<3><<<pgrid, blk, 0, stream>>>(qkvb, mask, xb);
}

// Round 13
// 127.984 us; speedup vs baseline: 2.4330x; 2.4330x over previous
//
#include <hip/hip_runtime.h>
#include <hip/hip_bf16.h>

#define B_NUM 2
#define S_LEN 2048
#define E_DIM 1024
#define H_NUM 16
#define D_DIM 64
#define QKV_LD 3072
// 1/sqrt(64) * log2(e): folded so softmax exp is a bare v_exp_f32 (exp2)
#define QSCALE_LOG2E 0.18033688011112042f

typedef __attribute__((ext_vector_type(8))) short bf16x8;
typedef __attribute__((ext_vector_type(8))) unsigned short u16x8;
typedef __attribute__((ext_vector_type(4))) unsigned short u16x4;
typedef __attribute__((ext_vector_type(4))) float f32x4;
typedef __attribute__((ext_vector_type(16))) float f32x16;
typedef __attribute__((ext_vector_type(2))) int i32x2;

static __device__ __forceinline__ unsigned short f2bf(float f) {
    union { float f; unsigned int u; } v; v.f = f;
    unsigned int r = v.u + 0x7fffu + ((v.u >> 16) & 1u);   // RNE
    return (unsigned short)(r >> 16);
}

static __device__ __forceinline__ unsigned cvtpk_bf16(float lo, float hi) {
    unsigned r;
    asm("v_cvt_pk_bf16_f32 %0, %1, %2" : "=v"(r) : "v"(lo), "v"(hi));
    return r;
}

// async global->LDS, 16B per lane; LDS dest = uniform base + lane*16
static __device__ __forceinline__ void gload16(const void* gsrc, void* ldst) {
    __builtin_amdgcn_global_load_lds(
        (const __attribute__((address_space(1))) unsigned int*)gsrc,
        (__attribute__((address_space(3))) unsigned int*)ldst, 16, 0, 0);
}

// ---------------------------------------------------------------------------
// fp32 -> bf16 bulk convert
// ---------------------------------------------------------------------------
__global__ __launch_bounds__(256)
void cvt_f32_bf16(const float* __restrict__ in, unsigned short* __restrict__ outp, int n4) {
    int i = blockIdx.x * blockDim.x + threadIdx.x;
    if (i < n4) {
        float4 f = ((const float4*)in)[i];
        u16x4 o = { f2bf(f.x), f2bf(f.y), f2bf(f.z), f2bf(f.w) };
        ((u16x4*)outp)[i] = o;
    }
}

// ---------------------------------------------------------------------------
// 128x128 bf16 MFMA GEMM, BK=64, 4 waves. (proven rounds 4-12)
// ---------------------------------------------------------------------------
template <bool OUT_BF16, bool QSCALE>
__global__ __launch_bounds__(256)
void gemm_bt_mfma128(const unsigned short* __restrict__ A,
                     const unsigned short* __restrict__ Bw,
                     void* __restrict__ Cv, int M, int N, int K) {
    __shared__ unsigned short As[128 * 64];
    __shared__ unsigned short Bs[128 * 64];
    char* const AsB = (char*)As;
    char* const BsB = (char*)Bs;
    const int tid  = threadIdx.x;
    const int lane = tid & 63;
    const int w    = tid >> 6;
    const int lg   = lane >> 4;
    const int lq   = lane & 15;
    const int bm = blockIdx.y * 128;
    const int bn = blockIdx.x * 128;
    const int wr = (w >> 1) * 64;
    const int wc = (w & 1) * 64;
    const int lrow8 = lane >> 3;
    const int gblk  = (lane & 7) ^ lrow8;

    f32x4 acc[4][4];
#pragma unroll
    for (int i = 0; i < 4; ++i)
#pragma unroll
        for (int j = 0; j < 4; ++j) acc[i][j] = (f32x4){0.f, 0.f, 0.f, 0.f};

    for (int k0 = 0; k0 < K; k0 += 64) {
        __syncthreads();
#pragma unroll
        for (int t = 0; t < 4; ++t) {
            const int c = w * 4 + t;
            const int row = c * 8 + lrow8;
            gload16(A + (size_t)(bm + row) * K + k0 + gblk * 8, AsB + c * 1024);
            gload16(Bw + (size_t)(bn + row) * K + k0 + gblk * 8, BsB + c * 1024);
        }
        __syncthreads();

        bf16x8 af[4][2], bfr[4][2];
#pragma unroll
        for (int rt = 0; rt < 4; ++rt) {
            const int row = wr + rt * 16 + lq;
            const int sz = (row & 7) << 4;
            af[rt][0] = *(const bf16x8*)(AsB + row * 128 + ((lg * 16)      ^ sz));
            af[rt][1] = *(const bf16x8*)(AsB + row * 128 + ((64 + lg * 16) ^ sz));
        }
#pragma unroll
        for (int ct = 0; ct < 4; ++ct) {
            const int row = wc + ct * 16 + lq;
            const int sz = (row & 7) << 4;
            bfr[ct][0] = *(const bf16x8*)(BsB + row * 128 + ((lg * 16)      ^ sz));
            bfr[ct][1] = *(const bf16x8*)(BsB + row * 128 + ((64 + lg * 16) ^ sz));
        }
#pragma unroll
        for (int rt = 0; rt < 4; ++rt)
#pragma unroll
            for (int ct = 0; ct < 4; ++ct) {
                acc[rt][ct] = __builtin_amdgcn_mfma_f32_16x16x32_bf16(af[rt][0], bfr[ct][0], acc[rt][ct], 0, 0, 0);
                acc[rt][ct] = __builtin_amdgcn_mfma_f32_16x16x32_bf16(af[rt][1], bfr[ct][1], acc[rt][ct], 0, 0, 0);
            }
    }

#pragma unroll
    for (int rt = 0; rt < 4; ++rt)
#pragma unroll
        for (int ct = 0; ct < 4; ++ct) {
            const int row = bm + wr + rt * 16 + lg * 4;
            const int col = bn + wc + ct * 16 + lq;
            float scale = 1.f;
            if constexpr (QSCALE) scale = ((col % 192) < 64) ? QSCALE_LOG2E : 1.f;
#pragma unroll
            for (int r = 0; r < 4; ++r) {
                float vv = acc[rt][ct][r] * scale;
                if constexpr (OUT_BF16)
                    ((unsigned short*)Cv)[(size_t)(row + r) * N + col] = f2bf(vv);
                else
                    ((float*)Cv)[(size_t)(row + r) * N + col] = vv;
            }
        }
}

// ---------------------------------------------------------------------------
// 64x64 bf16 MFMA GEMM (known-good; output projection)
// ---------------------------------------------------------------------------
template <bool OUT_BF16, bool QSCALE>
__global__ __launch_bounds__(256)
void gemm_bt_mfma(const unsigned short* __restrict__ A,
                  const unsigned short* __restrict__ Bw,
                  void* __restrict__ Cv, int M, int N, int K) {
    __shared__ unsigned short As[64 * 64];
    __shared__ unsigned short Bs[64 * 64];
    char* const AsB = (char*)As;
    char* const BsB = (char*)Bs;
    const int tid  = threadIdx.x;
    const int lane = tid & 63;
    const int w    = tid >> 6;
    const int lg   = lane >> 4;
    const int lq   = lane & 15;
    const int bm = blockIdx.y * 64;
    const int bn = blockIdx.x * 64;
    const int wr = (w >> 1) * 32;
    const int wc = (w & 1) * 32;
    const int sr = tid >> 2;
    const int sc = (tid & 3) * 16;
    const int swzS = (sr & 7) << 4;

    f32x4 acc[2][2];
#pragma unroll
    for (int i = 0; i < 2; ++i)
#pragma unroll
        for (int j = 0; j < 2; ++j) acc[i][j] = (f32x4){0.f, 0.f, 0.f, 0.f};

    const unsigned short* ap = A  + (size_t)(bm + sr) * K + sc;
    const unsigned short* bp = Bw + (size_t)(bn + sr) * K + sc;

    for (int k0 = 0; k0 < K; k0 += 64) {
        __syncthreads();
        u16x8 av0 = *(const u16x8*)(ap + k0);
        u16x8 av1 = *(const u16x8*)(ap + k0 + 8);
        u16x8 bv0 = *(const u16x8*)(bp + k0);
        u16x8 bv1 = *(const u16x8*)(bp + k0 + 8);
        *(u16x8*)(AsB + sr * 128 + ((sc * 2)      ^ swzS)) = av0;
        *(u16x8*)(AsB + sr * 128 + ((sc * 2 + 16) ^ swzS)) = av1;
        *(u16x8*)(BsB + sr * 128 + ((sc * 2)      ^ swzS)) = bv0;
        *(u16x8*)(BsB + sr * 128 + ((sc * 2 + 16) ^ swzS)) = bv1;
        __syncthreads();

        bf16x8 af[2][2], bfr[2][2];
#pragma unroll
        for (int rt = 0; rt < 2; ++rt) {
            const int row = wr + rt * 16 + lq;
            const int sz = (row & 7) << 4;
            af[rt][0] = *(const bf16x8*)(AsB + row * 128 + ((lg * 16)      ^ sz));
            af[rt][1] = *(const bf16x8*)(AsB + row * 128 + ((64 + lg * 16) ^ sz));
        }
#pragma unroll
        for (int ct = 0; ct < 2; ++ct) {
            const int row = wc + ct * 16 + lq;
            const int sz = (row & 7) << 4;
            bfr[ct][0] = *(const bf16x8*)(BsB + row * 128 + ((lg * 16)      ^ sz));
            bfr[ct][1] = *(const bf16x8*)(BsB + row * 128 + ((64 + lg * 16) ^ sz));
        }
#pragma unroll
        for (int rt = 0; rt < 2; ++rt)
#pragma unroll
            for (int ct = 0; ct < 2; ++ct) {
                acc[rt][ct] = __builtin_amdgcn_mfma_f32_16x16x32_bf16(af[rt][0], bfr[ct][0], acc[rt][ct], 0, 0, 0);
                acc[rt][ct] = __builtin_amdgcn_mfma_f32_16x16x32_bf16(af[rt][1], bfr[ct][1], acc[rt][ct], 0, 0, 0);
            }
    }

#pragma unroll
    for (int rt = 0; rt < 2; ++rt)
#pragma unroll
        for (int ct = 0; ct < 2; ++ct) {
            const int row = bm + wr + rt * 16 + lg * 4;
            const int col = bn + wc + ct * 16 + lq;
            float scale = 1.f;
            if constexpr (QSCALE) scale = ((col % 192) < 64) ? QSCALE_LOG2E : 1.f;
#pragma unroll
            for (int r = 0; r < 4; ++r) {
                float vv = acc[rt][ct][r] * scale;
                if constexpr (OUT_BF16)
                    ((unsigned short*)Cv)[(size_t)(row + r) * N + col] = f2bf(vv);
                else
                    ((float*)Cv)[(size_t)(row + r) * N + col] = vv;
            }
        }
}

// ---------------------------------------------------------------------------
// Flash attention v13: CROSS-TILE PIPELINED (from the round-12 ablation:
// QK path alone 19.5us, PV path alone 19.5us, both 73.5us -> the intra-tile
// QK->cvtpk->PV dependency chain is the bottleneck). Round t computes
// sNext = bias + QK(t+1) (independent) and consumes sCur = S(t) via
// exp2 -> cvtpk -> PV(t), so the two MFMA clusters in each round have no
// data dependency and their latency chains overlap.
// K staged 2 ahead (3 buffers, gload_lds, ISSUED BEFORE the V reg loads so
// the V-write auto-wait retires K(t+2) by end of round t -> K(t+1) is
// always landed+barrier-visible when QK(t+1) runs in round t).
// Barrier = lgkmcnt-only + raw s_barrier (K gloads fly across, v7-style).
// No-max softmax (p = exp2(bias + s)); bias row staged once.
// ---------------------------------------------------------------------------
__global__ __launch_bounds__(256)
void attn_v13(const unsigned short* __restrict__ qkv, const int* __restrict__ mask,
              unsigned short* __restrict__ vout) {
    __shared__ __align__(16) char KsP[3][8192];
    __shared__ __align__(16) char VtP[2][8192];
    __shared__ __align__(16) float BiasF[S_LEN];

    const int tid  = threadIdx.x;
    const int lane = tid & 63;
    const int w    = tid >> 6;
    const int ln   = lane & 31;
    const int hi   = lane >> 5;
    const int q0 = blockIdx.x * 128;
    const int h  = blockIdx.y;
    const int b  = blockIdx.z;
    const unsigned short* const kv =
        qkv + (size_t)b * S_LEN * QKV_LD + (size_t)h * (3 * D_DIM);

    {   // stage full bias row once
        const int4* mr = (const int4*)(mask + (size_t)b * S_LEN);
        int4 m0 = mr[tid * 2];
        int4 m1 = mr[tid * 2 + 1];
        float4 f0 = { m0.x ? 0.f : -30000.f, m0.y ? 0.f : -30000.f,
                      m0.z ? 0.f : -30000.f, m0.w ? 0.f : -30000.f };
        float4 f1 = { m1.x ? 0.f : -30000.f, m1.y ? 0.f : -30000.f,
                      m1.z ? 0.f : -30000.f, m1.w ? 0.f : -30000.f };
        ((float4*)BiasF)[tid * 2]     = f0;
        ((float4*)BiasF)[tid * 2 + 1] = f1;
    }

    // Q B-frags (pre-scaled by 0.125*log2e)
    bf16x8 qf[4];
    {
        const unsigned short* qp = kv + (size_t)(q0 + w * 32 + ln) * QKV_LD + hi * 8;
#pragma unroll
        for (int kk = 0; kk < 4; ++kk)
            qf[kk] = *(const bf16x8*)(qp + kk * 16);
    }

    const int lrow8 = lane >> 3;
    const int gblk  = (lane & 7) ^ lrow8;
    const int vkb = (tid & 15) * 4;
    const int vdb = (tid >> 4) * 4;

    // ---- prologue: K(0)->buf0, K(1)->buf1, V(0)->buf0; full drain ----
    {
#pragma unroll
        for (int t = 0; t < 2; ++t) {
            const int c = w * 2 + t;
            gload16(kv + (size_t)(c * 8 + lrow8) * QKV_LD + D_DIM + gblk * 8,
                    KsP[0] + c * 1024);
            gload16(kv + (size_t)(64 + c * 8 + lrow8) * QKV_LD + D_DIM + gblk * 8,
                    KsP[1] + c * 1024);
        }
        u16x4 vr[4];
#pragma unroll
        for (int i = 0; i < 4; ++i)
            vr[i] = *(const u16x4*)(kv + (size_t)(vkb + i) * QKV_LD + 2 * D_DIM + vdb);
#pragma unroll
        for (int j = 0; j < 4; ++j) {
            u16x4 o = { vr[0][j], vr[1][j], vr[2][j], vr[3][j] };
            const int row = vdb + j;
            *(u16x4*)(VtP[0] + row * 128 + ((vkb * 2) ^ ((row & 7) << 4))) = o;
        }
    }
    __builtin_amdgcn_sched_barrier(0);
    asm volatile("s_waitcnt vmcnt(0) lgkmcnt(0)" ::: "memory");
    __builtin_amdgcn_s_barrier();
    __builtin_amdgcn_sched_barrier(0);

    f32x16 accO[2];
#pragma unroll
    for (int dt = 0; dt < 2; ++dt)
#pragma unroll
        for (int r = 0; r < 16; ++r) accO[dt][r] = 0.f;
    f32x4 rsumv = (f32x4){0.f, 0.f, 0.f, 0.f};

    const int kswz = (ln & 7) << 4;

    // ---- S(0) = bias(0) + QK(0) from KsP[0] ----
    f32x16 sCur[2];
#pragma unroll
    for (int ks = 0; ks < 2; ++ks) {
#pragma unroll
        for (int m = 0; m < 4; ++m) {
            f32x4 b4 = *(const f32x4*)(&BiasF[ks * 32 + m * 8 + hi * 4]);
#pragma unroll
            for (int i = 0; i < 4; ++i) sCur[ks][m * 4 + i] = b4[i];
        }
        const int krow = ks * 32 + ln;
#pragma unroll
        for (int kk = 0; kk < 4; ++kk) {
            bf16x8 kf = *(const bf16x8*)(KsP[0] + krow * 128 + (((kk * 16 + hi * 8) * 2) ^ kswz));
            sCur[ks] = __builtin_amdgcn_mfma_f32_32x32x16_bf16(kf, qf[kk], sCur[ks], 0, 0, 0);
        }
    }

    const int NT = S_LEN / 64;   // 32
    int cur3 = 0;                // t % 3 (K buffer of tile t)
    for (int it = 0; it < NT; ++it) {
        const int curv = it & 1;
        const int kv0 = it * 64;
        char* const VtC = VtP[curv];
        const int nxt3 = (cur3 == 2) ? 0 : cur3 + 1;   // K(t+1) buffer
        const int k2b  = (nxt3 == 2) ? 0 : nxt3 + 1;   // K(t+2) buffer
        const bool pfV = (it + 1 < NT);
        const bool pfK = (it + 2 < NT);

        // ---- issue K(t+2) gloads FIRST (retired by this round's V-wait) ----
        if (pfK) {
            const int kvn2 = kv0 + 128;
#pragma unroll
            for (int t = 0; t < 2; ++t) {
                const int c = w * 2 + t;
                gload16(kv + (size_t)(kvn2 + c * 8 + lrow8) * QKV_LD + D_DIM + gblk * 8,
                        KsP[k2b] + c * 1024);
            }
        }
        // ---- then issue V(t+1) reg loads ----
        u16x4 vr[4];
        if (pfV) {
            const int kvn = kv0 + 64;
#pragma unroll
            for (int i = 0; i < 4; ++i)
                vr[i] = *(const u16x4*)(kv + (size_t)(kvn + vkb + i) * QKV_LD + 2 * D_DIM + vdb);
        }

        // ---- [A] sNext = bias(t+1) + QK(t+1)  (independent of this tile's PV) ----
        f32x16 sNext[2];
        if (pfV) {
            const int kvn = kv0 + 64;
            __builtin_amdgcn_s_setprio(1);
#pragma unroll
            for (int ks = 0; ks < 2; ++ks) {
#pragma unroll
                for (int m = 0; m < 4; ++m) {
                    f32x4 b4 = *(const f32x4*)(&BiasF[kvn + ks * 32 + m * 8 + hi * 4]);
#pragma unroll
                    for (int i = 0; i < 4; ++i) sNext[ks][m * 4 + i] = b4[i];
                }
                const int krow = ks * 32 + ln;
#pragma unroll
                for (int kk = 0; kk < 4; ++kk) {
                    bf16x8 kf = *(const bf16x8*)(KsP[nxt3] + krow * 128 + (((kk * 16 + hi * 8) * 2) ^ kswz));
                    sNext[ks] = __builtin_amdgcn_mfma_f32_32x32x16_bf16(kf, qf[kk], sNext[ks], 0, 0, 0);
                }
            }
            __builtin_amdgcn_s_setprio(0);
        }

        // ---- [B] p = exp2(sCur); row sums; pb = cvtpk+permlane ----
#pragma unroll
        for (int ks = 0; ks < 2; ++ks)
#pragma unroll
            for (int r = 0; r < 16; ++r) {
                float p = __builtin_amdgcn_exp2f(sCur[ks][r]);
                sCur[ks][r] = p;
                rsumv[r & 3] += p;
            }
        bf16x8 pb[4];
#pragma unroll
        for (int ks = 0; ks < 2; ++ks) {
            unsigned wA[4], wB[4];
#pragma unroll
            for (int m = 0; m < 4; ++m) {
                wA[m] = cvtpk_bf16(sCur[ks][4 * m + 0], sCur[ks][4 * m + 1]);
                wB[m] = cvtpk_bf16(sCur[ks][4 * m + 2], sCur[ks][4 * m + 3]);
            }
#pragma unroll
            for (int t = 0; t < 2; ++t) {
                i32x2 ra = __builtin_amdgcn_permlane32_swap((int)wA[2 * t], (int)wA[2 * t + 1], false, false);
                i32x2 rb = __builtin_amdgcn_permlane32_swap((int)wB[2 * t], (int)wB[2 * t + 1], false, false);
                union { unsigned u[4]; bf16x8 v; } uu;
                uu.u[0] = (unsigned)ra[0];
                uu.u[1] = (unsigned)rb[0];
                uu.u[2] = (unsigned)ra[1];
                uu.u[3] = (unsigned)rb[1];
                pb[ks * 2 + t] = uu.v;
            }
        }

        // ---- [C] O^T += V^T(t) P^T(t) ----
        __builtin_amdgcn_s_setprio(1);
#pragma unroll
        for (int dt = 0; dt < 2; ++dt) {
            const int drow = dt * 32 + ln;
            const int swz = (ln & 7) << 4;
#pragma unroll
            for (int n = 0; n < 4; ++n) {
                bf16x8 va = *(const bf16x8*)(VtC + drow * 128 + (((n * 16 + hi * 8) * 2) ^ swz));
                accO[dt] = __builtin_amdgcn_mfma_f32_32x32x16_bf16(va, pb[n], accO[dt], 0, 0, 0);
            }
        }
        __builtin_amdgcn_s_setprio(0);

        // ---- [D] V(t+1) regs -> LDS; lgkm-only barrier (K gloads fly on) ----
        if (pfV) {
#pragma unroll
            for (int j = 0; j < 4; ++j) {
                u16x4 o = { vr[0][j], vr[1][j], vr[2][j], vr[3][j] };
                const int row = vdb + j;
                *(u16x4*)(VtP[curv ^ 1] + row * 128 + ((vkb * 2) ^ ((row & 7) << 4))) = o;
            }
            __builtin_amdgcn_sched_barrier(0);
            asm volatile("s_waitcnt lgkmcnt(0)" ::: "memory");
            __builtin_amdgcn_s_barrier();
            __builtin_amdgcn_sched_barrier(0);
            // ping-pong: S(t+1) becomes current
            sCur[0] = sNext[0];
            sCur[1] = sNext[1];
        }

        cur3 = nxt3;
    }

    // ---- epilogue: partner-reduce row sum, normalize, store bf16 ----
    float rsum = rsumv[0] + rsumv[1] + rsumv[2] + rsumv[3];
    {
        i32x2 rr = __builtin_amdgcn_permlane32_swap(__float_as_int(rsum), __float_as_int(rsum), false, false);
        rsum = __int_as_float(rr[0]) + __int_as_float(rr[1]);
    }
    const float inv = 1.f / rsum;
    unsigned short* op = vout + (size_t)(b * S_LEN + q0 + w * 32 + ln) * E_DIM + h * D_DIM;
#pragma unroll
    for (int dt = 0; dt < 2; ++dt)
#pragma unroll
        for (int m = 0; m < 4; ++m) {
            u16x4 o;
#pragma unroll
            for (int i = 0; i < 4; ++i) o[i] = f2bf(accO[dt][4 * m + i] * inv);
            *(u16x4*)(op + dt * 32 + m * 8 + hi * 4) = o;
        }
}

// ---------------------------------------------------------------------------
extern "C" void kernel_launch(void* const* d_in, const int* in_sizes, int n_in,
                              void* d_out, int out_size, void* d_ws, size_t ws_size,
                              hipStream_t stream) {
    const float* x      = (const float*)d_in[0];
    const int*   mask   = (const int*)d_in[1];
    const float* w_qkv  = (const float*)d_in[2];
    const float* w_o    = (const float*)d_in[3];
    float*       out    = (float*)d_out;

    const int M = B_NUM * S_LEN;     // 4096
    unsigned short* qkvb = (unsigned short*)d_ws;                    // M x 3E
    unsigned short* vbuf = qkvb + (size_t)M * 3 * E_DIM;             // M x E
    unsigned short* xb   = vbuf + (size_t)M * E_DIM;                 // M x E
    unsigned short* wqb  = xb   + (size_t)M * E_DIM;                 // 3E x E
    unsigned short* wob  = wqb  + (size_t)3 * E_DIM * E_DIM;         // E x E

    dim3 blk(256);
    {
        int n4;
        n4 = M * E_DIM / 4;
        cvt_f32_bf16<<<dim3((n4 + 255) / 256), blk, 0, stream>>>(x, xb, n4);
        n4 = 3 * E_DIM * E_DIM / 4;
        cvt_f32_bf16<<<dim3((n4 + 255) / 256), blk, 0, stream>>>(w_qkv, wqb, n4);
        n4 = E_DIM * E_DIM / 4;
        cvt_f32_bf16<<<dim3((n4 + 255) / 256), blk, 0, stream>>>(w_o, wob, n4);
    }

    // QKV projection (q columns pre-scaled by 0.125*log2e), bf16 out
    gemm_bt_mfma128<true, true><<<dim3(3 * E_DIM / 128, M / 128), blk, 0, stream>>>(
        xb, wqb, qkvb, M, 3 * E_DIM, E_DIM);

    // flash attention v13 (cross-tile pipelined QK/PV)
    attn_v13<<<dim3(S_LEN / 128, H_NUM, B_NUM), blk, 0, stream>>>(qkvb, mask, vbuf);

    // output projection, fp32 out
    gemm_bt_mfma<false, false><<<dim3(E_DIM / 64, M / 64), blk, 0, stream>>>(
        vbuf, wob, out, M, E_DIM, E_DIM);
}